// Round 4
// baseline (157.821 us; speedup 1.0000x reference)
//
#include <hip/hip_runtime.h>

// B=16384 rows, D=1024. comb: (B, 2D) f32 = [mean | std]; next_state: (B, D) f32.
// out = mean over rows of [ sum_j log(std^2) + sum_j (mean-ns)^2/std^2 ].
// Flat sum over all B*D elements / B. Pure streaming reduction, memory-bound.
//
// Single fused kernel + threadfence-reduction. R3 lesson: the "counter needs
// no init" modulo trick was WRONG — with poison start S, the ticket hitting
// (S+k) % NBLK == NBLK-1 arrives at position k+1 < NBLK, i.e. BEFORE all
// partials are written. Fix: zero the counter every call via a 4-byte
// hipMemsetAsync on the stream (graph-capture-legal; the harness itself
// records memset nodes). Then ticket == NBLK-1 is truly the last arrival.
// partials use device-scope (AGENT) atomics: per-XCD L2s are not coherent.

constexpr int BDIM = 256;
constexpr int NROWS = 16384;
constexpr int SDIM = 1024;
constexpr int ROWS_PER_BLOCK = 8;
constexpr int NBLK = NROWS / ROWS_PER_BLOCK;  // 2048 blocks = 8/CU, fully resident

__device__ __forceinline__ void accum_elem(float m, float s, float n,
                                           float& quad, float& lg2) {
  float var = s * s;
  float d = m - n;
  lg2 += __builtin_amdgcn_logf(var);            // log2(var); scale by ln2 once
  quad += d * d * __builtin_amdgcn_rcpf(var);   // fast rcp, ~1 ulp
}

__device__ __forceinline__ void accum4(float4 m, float4 s, float4 n,
                                       float& quad, float& lg2) {
  accum_elem(m.x, s.x, n.x, quad, lg2);
  accum_elem(m.y, s.y, n.y, quad, lg2);
  accum_elem(m.z, s.z, n.z, quad, lg2);
  accum_elem(m.w, s.w, n.w, quad, lg2);
}

__global__ __launch_bounds__(BDIM, 8) void loss_fused(
    const float4* __restrict__ comb, const float4* __restrict__ ns,
    float* __restrict__ partials, unsigned* __restrict__ counter,
    float* __restrict__ out) {
  const int t = threadIdx.x;
  const int b = blockIdx.x;
  constexpr int CS = 2 * SDIM / 4;  // 512 float4 per comb row
  constexpr int NS = SDIM / 4;      // 256 float4 per ns row

  // Two rows per unrolled step: 6 float4 loads batched before any use.
  float q0 = 0.f, q1 = 0.f, l0 = 0.f, l1 = 0.f;
  const long row0 = (long)b * ROWS_PER_BLOCK;
#pragma unroll
  for (int r = 0; r < ROWS_PER_BLOCK; r += 2) {
    const float4* c0 = comb + (row0 + r) * CS;
    const float4* n0p = ns + (row0 + r) * NS;
    float4 m0 = c0[t];
    float4 s0 = c0[NS + t];
    float4 m1 = c0[CS + t];
    float4 s1 = c0[CS + NS + t];
    float4 n0 = n0p[t];
    float4 n1 = n0p[NS + t];
    accum4(m0, s0, n0, q0, l0);
    accum4(m1, s1, n1, q1, l1);
  }
  float acc = (q0 + q1) + 0.69314718055994531f * (l0 + l1);

  // wave64 reduce, then cross-wave via LDS
#pragma unroll
  for (int off = 32; off > 0; off >>= 1) acc += __shfl_down(acc, off, 64);

  __shared__ float wsum[BDIM / 64];
  __shared__ int islast;
  if ((t & 63) == 0) wsum[t >> 6] = acc;
  __syncthreads();

  if (t == 0) {
    float mypart = (wsum[0] + wsum[1]) + (wsum[2] + wsum[3]);
    // Device-scope store: bypasses non-coherent per-XCD caches.
    __hip_atomic_store(&partials[b], mypart, __ATOMIC_RELEASE,
                       __HIP_MEMORY_SCOPE_AGENT);
    unsigned ticket = __hip_atomic_fetch_add(counter, 1u, __ATOMIC_ACQ_REL,
                                             __HIP_MEMORY_SCOPE_AGENT);
    islast = (ticket == (unsigned)(NBLK - 1));  // counter zeroed per call
  }
  __syncthreads();

  if (islast) {            // block-uniform condition; true 2048th arrival
    float a = 0.f;
#pragma unroll
    for (int i = 0; i < NBLK / BDIM; ++i)
      a += __hip_atomic_load(&partials[i * BDIM + t], __ATOMIC_ACQUIRE,
                             __HIP_MEMORY_SCOPE_AGENT);
#pragma unroll
    for (int off = 32; off > 0; off >>= 1) a += __shfl_down(a, off, 64);
    __syncthreads();       // safe to reuse wsum
    if ((t & 63) == 0) wsum[t >> 6] = a;
    __syncthreads();
    if (t == 0)
      out[0] = ((wsum[0] + wsum[1]) + (wsum[2] + wsum[3])) *
               (1.0f / (float)NROWS);
  }
}

extern "C" void kernel_launch(void* const* d_in, const int* in_sizes, int n_in,
                              void* d_out, int out_size, void* d_ws,
                              size_t ws_size, hipStream_t stream) {
  const float4* comb = (const float4*)d_in[0];
  // d_in[1] = state_dim (scalar on device) — statically 1024, unused.
  const float4* ns = (const float4*)d_in[2];
  float* partials = (float*)d_ws;                      // 2048 floats
  unsigned* counter = (unsigned*)((char*)d_ws + NBLK * sizeof(float));
  float* out = (float*)d_out;

  // Zero the arrival counter every call (graph-legal async memset node).
  hipMemsetAsync(counter, 0, sizeof(unsigned), stream);
  loss_fused<<<NBLK, BDIM, 0, stream>>>(comb, ns, partials, counter, out);
}

// Round 5
// 46.720 us; speedup vs baseline: 3.3780x; 3.3780x over previous
//
#include <hip/hip_runtime.h>

// B=16384 rows, D=1024. comb: (B, 2D) f32 = [mean | std]; next_state: (B, D) f32.
// out = mean over rows of [ sum_j log(std^2) + sum_j (mean-ns)^2/var ].
// Pure streaming reduction, memory-bound (192 MiB read / ~32 us roofline).
//
// Fused single kernel + arrival-ticket finisher.
// R4 lesson: ACQUIRE/RELEASE at agent scope emit buffer_wbl2/buffer_inv (full
// L2 writeback+invalidate) per block -> 2048 L2 flushes serialized the memory
// system (4.4x regression). Coherence across non-coherent per-XCD L2s needs
// only the SCOPE (agent => sc1 write-through/read-through), not the ordering
// fences. So: all cross-block traffic is RELAXED+AGENT; the one required
// ordering (my partial visible before my ticket) is a manual
// s_waitcnt vmcnt(0) -- the partial store is sc1 write-through, so vmcnt
// retirement == arrival at the coherence point. Reader side is control-
// dependent on the RMW result; relaxed agent loads read through the caches.
// Counter is zeroed each call by a 4-byte hipMemsetAsync (graph-legal).

constexpr int BDIM = 256;
constexpr int NROWS = 16384;
constexpr int SDIM = 1024;
constexpr int ROWS_PER_BLOCK = 8;
constexpr int NBLK = NROWS / ROWS_PER_BLOCK;  // 2048 blocks, fully resident

__device__ __forceinline__ void accum_elem(float m, float s, float n,
                                           float& quad, float& lg2) {
  float var = s * s;
  float d = m - n;
  lg2 += __builtin_amdgcn_logf(var);            // log2(var); scale by ln2 once
  quad += d * d * __builtin_amdgcn_rcpf(var);   // fast rcp, ~1 ulp
}

__device__ __forceinline__ void accum4(float4 m, float4 s, float4 n,
                                       float& quad, float& lg2) {
  accum_elem(m.x, s.x, n.x, quad, lg2);
  accum_elem(m.y, s.y, n.y, quad, lg2);
  accum_elem(m.z, s.z, n.z, quad, lg2);
  accum_elem(m.w, s.w, n.w, quad, lg2);
}

__global__ __launch_bounds__(BDIM) void loss_fused(
    const float4* __restrict__ comb, const float4* __restrict__ ns,
    float* __restrict__ partials, unsigned* __restrict__ counter,
    float* __restrict__ out) {
  const int t = threadIdx.x;
  const int b = blockIdx.x;
  constexpr int CS = 2 * SDIM / 4;  // 512 float4 per comb row
  constexpr int NS = SDIM / 4;      // 256 float4 per ns row

  float q0 = 0.f, q1 = 0.f, l0 = 0.f, l1 = 0.f;
  const long row0 = (long)b * ROWS_PER_BLOCK;
#pragma unroll
  for (int r = 0; r < ROWS_PER_BLOCK; r += 2) {
    const float4* c0 = comb + (row0 + r) * CS;
    const float4* n0p = ns + (row0 + r) * NS;
    float4 m0 = c0[t];
    float4 s0 = c0[NS + t];
    float4 m1 = c0[CS + t];
    float4 s1 = c0[CS + NS + t];
    float4 n0 = n0p[t];
    float4 n1 = n0p[NS + t];
    accum4(m0, s0, n0, q0, l0);
    accum4(m1, s1, n1, q1, l1);
  }
  float acc = (q0 + q1) + 0.69314718055994531f * (l0 + l1);

  // wave64 reduce, then cross-wave via LDS
#pragma unroll
  for (int off = 32; off > 0; off >>= 1) acc += __shfl_down(acc, off, 64);

  __shared__ float wsum[BDIM / 64];
  __shared__ int islast;
  if ((t & 63) == 0) wsum[t >> 6] = acc;
  __syncthreads();

  if (t == 0) {
    float mypart = (wsum[0] + wsum[1]) + (wsum[2] + wsum[3]);
    // Relaxed agent-scope store: sc1 write-through to coherence point,
    // NO L2 writeback fence.
    __hip_atomic_store(&partials[b], mypart, __ATOMIC_RELAXED,
                       __HIP_MEMORY_SCOPE_AGENT);
    // Manual release: wait until the write-through has retired (reached the
    // coherence point) before taking a ticket.
    asm volatile("s_waitcnt vmcnt(0)" ::: "memory");
    unsigned ticket = __hip_atomic_fetch_add(counter, 1u, __ATOMIC_RELAXED,
                                             __HIP_MEMORY_SCOPE_AGENT);
    islast = (ticket == (unsigned)(NBLK - 1));  // counter zeroed per call
  }
  __syncthreads();

  if (islast) {            // block-uniform; true 2048th arrival
    float a = 0.f;
#pragma unroll
    for (int i = 0; i < NBLK / BDIM; ++i)
      a += __hip_atomic_load(&partials[i * BDIM + t], __ATOMIC_RELAXED,
                             __HIP_MEMORY_SCOPE_AGENT);
#pragma unroll
    for (int off = 32; off > 0; off >>= 1) a += __shfl_down(a, off, 64);
    __syncthreads();       // safe to reuse wsum
    if ((t & 63) == 0) wsum[t >> 6] = a;
    __syncthreads();
    if (t == 0)
      out[0] = ((wsum[0] + wsum[1]) + (wsum[2] + wsum[3])) *
               (1.0f / (float)NROWS);
  }
}

extern "C" void kernel_launch(void* const* d_in, const int* in_sizes, int n_in,
                              void* d_out, int out_size, void* d_ws,
                              size_t ws_size, hipStream_t stream) {
  const float4* comb = (const float4*)d_in[0];
  // d_in[1] = state_dim (scalar on device) — statically 1024, unused.
  const float4* ns = (const float4*)d_in[2];
  float* partials = (float*)d_ws;                      // 2048 floats
  unsigned* counter = (unsigned*)((char*)d_ws + NBLK * sizeof(float));
  float* out = (float*)d_out;

  // Zero the arrival counter every call (graph-legal async memset node).
  hipMemsetAsync(counter, 0, sizeof(unsigned), stream);
  loss_fused<<<NBLK, BDIM, 0, stream>>>(comb, ns, partials, counter, out);
}

// Round 6
// 36.138 us; speedup vs baseline: 4.3672x; 1.2928x over previous
//
#include <hip/hip_runtime.h>

// B=16384 rows, D=1024. comb: (B, 2D) f32 = [mean | std]; next_state: (B, D) f32.
// out = mean over rows of [ sum_j log(std^2) + sum_j (mean-ns)^2/var ].
// Pure streaming reduction: 192 MiB read, 4 B written -> memory-bound,
// roofline ~32 us at the 6.3 TB/s measured streaming ceiling.
//
// Structure: two dispatches (R1, proven 35.5 us). Rounds 2-5 showed every
// single-dispatch fusion re-buys the saved launch gap in cross-XCD coherence
// costs: acquire/release at agent scope = per-block L2 writeback/invalidate
// (4.4x regression, R4); relaxed agent atomics + ticket = same-address RMW
// burst + uncached finisher tail (+11 us, R5). Stream-edge ordering between
// two dispatches provides coherence for free. Finisher is one wave.

constexpr int BDIM = 256;
constexpr int NROWS = 16384;
constexpr int SDIM = 1024;
constexpr int ROWS_PER_BLOCK = 8;
constexpr int NBLK = NROWS / ROWS_PER_BLOCK;  // 2048 blocks = 8/CU, fully resident

__device__ __forceinline__ void accum_elem(float m, float s, float n,
                                           float& quad, float& lg2) {
  float var = s * s;
  float d = m - n;
  lg2 += __builtin_amdgcn_logf(var);            // log2(var); scale by ln2 once
  quad += d * d * __builtin_amdgcn_rcpf(var);   // fast rcp, ~1 ulp
}

__device__ __forceinline__ void accum4(float4 m, float4 s, float4 n,
                                       float& quad, float& lg2) {
  accum_elem(m.x, s.x, n.x, quad, lg2);
  accum_elem(m.y, s.y, n.y, quad, lg2);
  accum_elem(m.z, s.z, n.z, quad, lg2);
  accum_elem(m.w, s.w, n.w, quad, lg2);
}

__global__ __launch_bounds__(BDIM, 8) void loss_partial(
    const float4* __restrict__ comb, const float4* __restrict__ ns,
    float* __restrict__ partials) {
  const int t = threadIdx.x;
  const int b = blockIdx.x;
  constexpr int CS = 2 * SDIM / 4;  // 512 float4 per comb row
  constexpr int NS = SDIM / 4;      // 256 float4 per ns row

  // Two rows per unrolled step: 6 float4 loads batched before any use.
  float q0 = 0.f, q1 = 0.f, l0 = 0.f, l1 = 0.f;
  const long row0 = (long)b * ROWS_PER_BLOCK;
#pragma unroll
  for (int r = 0; r < ROWS_PER_BLOCK; r += 2) {
    const float4* c0 = comb + (row0 + r) * CS;
    const float4* n0p = ns + (row0 + r) * NS;
    float4 m0 = c0[t];
    float4 s0 = c0[NS + t];
    float4 m1 = c0[CS + t];
    float4 s1 = c0[CS + NS + t];
    float4 n0 = n0p[t];
    float4 n1 = n0p[NS + t];
    accum4(m0, s0, n0, q0, l0);
    accum4(m1, s1, n1, q1, l1);
  }
  float acc = (q0 + q1) + 0.69314718055994531f * (l0 + l1);

  // wave64 reduce, then cross-wave via LDS
#pragma unroll
  for (int off = 32; off > 0; off >>= 1) acc += __shfl_down(acc, off, 64);

  __shared__ float wsum[BDIM / 64];
  if ((t & 63) == 0) wsum[t >> 6] = acc;
  __syncthreads();
  if (t == 0) partials[b] = (wsum[0] + wsum[1]) + (wsum[2] + wsum[3]);
}

// Single-wave finisher: 64 lanes x 32 sequential adds (fixed order,
// deterministic), then shfl reduce. No LDS, no __syncthreads.
__global__ __launch_bounds__(64) void loss_final(
    const float* __restrict__ partials, float* __restrict__ out) {
  const int t = threadIdx.x;  // 0..63
  float a = 0.f;
#pragma unroll
  for (int i = 0; i < NBLK / 64; ++i) a += partials[i * 64 + t];
#pragma unroll
  for (int off = 32; off > 0; off >>= 1) a += __shfl_down(a, off, 64);
  if (t == 0) out[0] = a * (1.0f / (float)NROWS);
}

extern "C" void kernel_launch(void* const* d_in, const int* in_sizes, int n_in,
                              void* d_out, int out_size, void* d_ws,
                              size_t ws_size, hipStream_t stream) {
  const float4* comb = (const float4*)d_in[0];
  // d_in[1] = state_dim (scalar on device) — statically 1024, unused.
  const float4* ns = (const float4*)d_in[2];
  float* partials = (float*)d_ws;  // 2048 floats = 8 KB scratch
  float* out = (float*)d_out;

  loss_partial<<<NBLK, BDIM, 0, stream>>>(comb, ns, partials);
  loss_final<<<1, 64, 0, stream>>>(partials, out);
}